// Round 1
// baseline (2510.424 us; speedup 1.0000x reference)
//
#include <hip/hip_runtime.h>
#include <hip/hip_bf16.h>

// LSTM-LL persistent kernel for MI355X (gfx950).
// B=8192, T=128, E=128, V=128, L=2. Each block owns 32 batch rows for all steps.

typedef __bf16 bf16x8 __attribute__((ext_vector_type(8)));
typedef float  f32x4  __attribute__((ext_vector_type(4)));

static __device__ __bf16 g_wcat[2 * 512 * 256];  // [layer][gate 4E][k: 0..127=Wih, 128..255=Whh]
static __device__ __bf16 g_wout[128 * 128];      // [v][e]
static __device__ __bf16 g_emb[128 * 128];       // [v][e]
static __device__ float  g_bias[2 * 512];        // b_ih + b_hh

__device__ __forceinline__ float frcp(float x) {
#if __has_builtin(__builtin_amdgcn_rcpf)
  return __builtin_amdgcn_rcpf(x);
#else
  return 1.0f / x;
#endif
}
__device__ __forceinline__ float fsig(float x) { return frcp(1.0f + __expf(-x)); }
__device__ __forceinline__ float ftanh(float x) {
  float e = __expf(2.0f * x);
  return 1.0f - 2.0f * frcp(e + 1.0f);
}

__global__ void prep_kernel(const float* __restrict__ Wih, const float* __restrict__ Whh,
                            const float* __restrict__ bih, const float* __restrict__ bhh,
                            const float* __restrict__ Wout, const float* __restrict__ emb) {
  int idx = blockIdx.x * 256 + threadIdx.x;
  if (idx < 2 * 512 * 256) {
    int k = idx & 255, g = (idx >> 8) & 511, l = idx >> 17;
    float v = (k < 128) ? Wih[(l * 512 + g) * 128 + k] : Whh[(l * 512 + g) * 128 + (k - 128)];
    g_wcat[idx] = (__bf16)v;
  }
  if (idx < 128 * 128) {
    g_wout[idx] = (__bf16)Wout[idx];
    g_emb[idx]  = (__bf16)emb[idx];
  }
  if (idx < 1024) g_bias[idx] = bih[idx] + bhh[idx];
}

__global__ __launch_bounds__(512, 2) void lstm_ll_kernel(
    const float* __restrict__ state, const int* __restrict__ tokens,
    const float* __restrict__ bout_g, float* __restrict__ out) {
  // All [r][128] bf16 LDS tiles use XOR swizzle  e ^= (r&7)<<3  (bank-conflict fix).
  __shared__ __align__(16) __bf16 embL[128 * 128];  // 32 KB
  __shared__ __align__(16) __bf16 h1L[32 * 128];    // 8 KB
  __shared__ __align__(16) __bf16 h2L[32 * 128];    // 8 KB
  __shared__ unsigned char tokL[128][32];           // 4 KB, transposed [t][r]
  __shared__ float wsum[8][32];                     // per-wave softmax partial sums
  __shared__ float llL[32];                         // per-row log-likelihood accum

  const int tid  = threadIdx.x;
  const int w    = tid >> 6;    // wave 0..7
  const int lane = tid & 63;
  const int lr   = lane & 15;
  const int lh   = lane >> 4;   // 0..3
  const int b0   = blockIdx.x * 32;

  // ---- stage LDS ----
  for (int it = tid; it < 128 * 16; it += 512) {  // embed: 2048 chunks of 8 bf16
    int base = it * 8;
    int row = base >> 7, e = base & 127;
    bf16x8 v = *(const bf16x8*)(g_emb + base);
    *(bf16x8*)(embL + row * 128 + (e ^ ((row & 7) << 3))) = v;
  }
  for (int it = tid; it < 32 * 128; it += 512) {
    int r = it & 31, t = it >> 5;
    tokL[t][r] = (unsigned char)tokens[(b0 + r) * 128 + t];
    h1L[it] = (__bf16)0.0f;
    h2L[it] = (__bf16)0.0f;
  }
  if (tid < 32) llL[tid] = 0.0f;
  __syncthreads();

  float bias1[4], bias2[4];
#pragma unroll
  for (int gg = 0; gg < 4; ++gg) {
    bias1[gg] = g_bias[gg * 128 + w * 16 + lr];
    bias2[gg] = g_bias[512 + gg * 128 + w * 16 + lr];
  }
  const float bo = bout_g[w * 16 + lr];
  float c1[2][4] = {}, c2[2][4] = {};

  // A-fragment from a swizzled [*][128] bf16 LDS tile: lane supplies row, k = kc*32+lh*8+j
  auto ldsA = [&](const __bf16* buf, int row, int kc) -> bf16x8 {
    return *(const bf16x8*)(buf + row * 128 + ((kc * 32 + lh * 8) ^ ((row & 7) << 3)));
  };

  f32x4 acc[2][4];

  // gates[32][512] = [x | h] @ Wcat^T ; wave w owns gate cols gg*128 + w*16 + [0,16)
  auto gates = [&](const __bf16* __restrict__ Wl, auto aloadLo, const __bf16* hbuf) {
#pragma unroll
    for (int mf = 0; mf < 2; ++mf)
#pragma unroll
      for (int gg = 0; gg < 4; ++gg)
        acc[mf][gg] = f32x4{0.f, 0.f, 0.f, 0.f};
#pragma unroll
    for (int kc = 0; kc < 8; ++kc) {
      bf16x8 a0, a1;
      if (kc < 4) { a0 = aloadLo(0, kc); a1 = aloadLo(1, kc); }
      else        { a0 = ldsA(hbuf, lr, kc - 4); a1 = ldsA(hbuf, 16 + lr, kc - 4); }
      const __bf16* wb = Wl + (w * 16 + lr) * 256 + kc * 32 + lh * 8;
#pragma unroll
      for (int gg = 0; gg < 4; ++gg) {
        bf16x8 b = *(const bf16x8*)(wb + gg * (128 * 256));
        acc[0][gg] = __builtin_amdgcn_mfma_f32_16x16x32_bf16(a0, b, acc[0][gg], 0, 0, 0);
        acc[1][gg] = __builtin_amdgcn_mfma_f32_16x16x32_bf16(a1, b, acc[1][gg], 0, 0, 0);
      }
    }
  };

  // LSTM cell elementwise; C/D frag mapping: row = mf*16 + lh*4 + j, col = w*16 + lr
  auto elem = [&](const float bias[4], float c[2][4], __bf16* hout) {
#pragma unroll
    for (int mf = 0; mf < 2; ++mf)
#pragma unroll
      for (int j = 0; j < 4; ++j) {
        float gi = acc[mf][0][j] + bias[0];
        float gf = acc[mf][1][j] + bias[1];
        float gc = acc[mf][2][j] + bias[2];
        float go = acc[mf][3][j] + bias[3];
        float cc = fsig(gf) * c[mf][j] + fsig(gi) * ftanh(gc);
        c[mf][j] = cc;
        float h = fsig(go) * ftanh(cc);
        int r = mf * 16 + lh * 4 + j;
        int e = w * 16 + lr;
        hout[r * 128 + (e ^ ((r & 7) << 3))] = (__bf16)h;
      }
  };

  // logits + sum-exp softmax (no max pass: |logit| <= ~11.4, exp cannot overflow)
  auto dologits = [&](int t) {
    f32x4 la[2];
    la[0] = f32x4{0.f, 0.f, 0.f, 0.f};
    la[1] = f32x4{0.f, 0.f, 0.f, 0.f};
#pragma unroll
    for (int kc = 0; kc < 4; ++kc) {
      bf16x8 a0 = ldsA(h2L, lr, kc);
      bf16x8 a1 = ldsA(h2L, 16 + lr, kc);
      bf16x8 b = *(const bf16x8*)(g_wout + (w * 16 + lr) * 128 + kc * 32 + lh * 8);
      la[0] = __builtin_amdgcn_mfma_f32_16x16x32_bf16(a0, b, la[0], 0, 0, 0);
      la[1] = __builtin_amdgcn_mfma_f32_16x16x32_bf16(a1, b, la[1], 0, 0, 0);
    }
    float lv[2][4];
#pragma unroll
    for (int mf = 0; mf < 2; ++mf)
#pragma unroll
      for (int j = 0; j < 4; ++j) {
        float v = la[mf][j] + bo;
        lv[mf][j] = v;
        float s = __expf(v);
        s += __shfl_xor(s, 1);
        s += __shfl_xor(s, 2);
        s += __shfl_xor(s, 4);
        s += __shfl_xor(s, 8);
        if (lr == 0) wsum[w][mf * 16 + lh * 4 + j] = s;
      }
    __syncthreads();
#pragma unroll
    for (int mf = 0; mf < 2; ++mf)
#pragma unroll
      for (int j = 0; j < 4; ++j) {
        int r = mf * 16 + lh * 4 + j;
        int tgt = (int)tokL[t + 1][r];
        if ((tgt >> 4) == w && (tgt & 15) == lr) {  // this lane owns logit[tgt] of row r
          float S = 0.f;
#pragma unroll
          for (int ww = 0; ww < 8; ++ww) S += wsum[ww][r];
          llL[r] += lv[mf][j] - __logf(S);
        }
      }
    __syncthreads();
  };

  auto aState = [&](int mf, int kc) -> bf16x8 {  // init step: x = state (f32 global)
    const float* p = state + (size_t)(b0 + mf * 16 + lr) * 128 + kc * 32 + lh * 8;
    f32x4 x0 = *(const f32x4*)p;
    f32x4 x1 = *(const f32x4*)(p + 4);
    bf16x8 rv;
#pragma unroll
    for (int j = 0; j < 4; ++j) { rv[j] = (__bf16)x0[j]; rv[4 + j] = (__bf16)x1[j]; }
    return rv;
  };
  auto aH1 = [&](int mf, int kc) -> bf16x8 { return ldsA(h1L, mf * 16 + lr, kc); };

  // ---- init step (get_init_state): one LSTM step on `state`, h=c=0 ----
  gates(g_wcat, aState, h1L);
  __syncthreads();
  elem(bias1, c1, h1L);
  __syncthreads();
  gates(g_wcat + 512 * 256, aH1, h2L);
  __syncthreads();
  elem(bias2, c2, h2L);
  __syncthreads();

  // ---- main loop: consume token t (0..126), predict token t+1 ----
  for (int t = 0; t < 127; ++t) {
    auto aEmb = [&](int mf, int kc) -> bf16x8 {
      int row = (int)tokL[t][mf * 16 + lr];
      return ldsA(embL, row, kc);
    };
    gates(g_wcat, aEmb, h1L);
    __syncthreads();
    elem(bias1, c1, h1L);
    __syncthreads();
    gates(g_wcat + 512 * 256, aH1, h2L);
    __syncthreads();
    elem(bias2, c2, h2L);
    __syncthreads();
    dologits(t);
  }

  if (tid < 32) out[b0 + tid] = llL[tid];
}

extern "C" void kernel_launch(void* const* d_in, const int* in_sizes, int n_in,
                              void* d_out, int out_size, void* d_ws, size_t ws_size,
                              hipStream_t stream) {
  const float* state  = (const float*)d_in[0];
  const int*   tokens = (const int*)d_in[1];
  const float* emb    = (const float*)d_in[2];
  const float* Wih    = (const float*)d_in[3];
  const float* Whh    = (const float*)d_in[4];
  const float* bih    = (const float*)d_in[5];
  const float* bhh    = (const float*)d_in[6];
  const float* Wout   = (const float*)d_in[7];
  const float* bout   = (const float*)d_in[8];
  float* out = (float*)d_out;

  prep_kernel<<<1024, 256, 0, stream>>>(Wih, Whh, bih, bhh, Wout, emb);
  lstm_ll_kernel<<<256, 512, 0, stream>>>(state, tokens, bout, out);
}

// Round 2
// 1224.439 us; speedup vs baseline: 2.0503x; 2.0503x over previous
//
#include <hip/hip_runtime.h>
#include <hip/hip_bf16.h>

// LSTM-LL v2: all recurrent weights resident (VGPR: Whh1/Whh2/Wout, LDS: Wih2),
// layer-1 input-weights folded into a precomputed per-token gate table (emb1).
// No per-step global weight streaming -> no spill pressure, no L2 dependence.
// B=8192, T=128, E=128, V=128, L=2. 256 blocks x 512 thr, 32 batch rows/block.

typedef __bf16 bf16x8 __attribute__((ext_vector_type(8)));
typedef float  f32x4  __attribute__((ext_vector_type(4)));

static __device__ __bf16 g_emb1[128 * 512];  // [v][4E] = emb[v] @ Wih1^T + b_ih1 + b_hh1

__device__ __forceinline__ float frcp(float x) {
#if __has_builtin(__builtin_amdgcn_rcpf)
  return __builtin_amdgcn_rcpf(x);
#else
  return 1.0f / x;
#endif
}
__device__ __forceinline__ float fsig(float x) { return frcp(1.0f + __expf(-x)); }
__device__ __forceinline__ float ftanh(float x) {
  float e = __expf(2.0f * x);
  return 1.0f - 2.0f * frcp(e + 1.0f);
}

// emb1[v][col] = dot(emb[v,:], Wih1[col,:]) + bih1[col] + bhh1[col]
__global__ void prep_emb1(const float* __restrict__ emb, const float* __restrict__ Wih,
                          const float* __restrict__ bih, const float* __restrict__ bhh) {
  __shared__ float embS[128 * 128];  // 64 KB
  __shared__ float wS[32 * 128];     // 16 KB
  const int tid = threadIdx.x, bc = blockIdx.x;
  for (int i = tid; i < 128 * 32; i += 512) ((f32x4*)embS)[i] = ((const f32x4*)emb)[i];
  for (int i = tid; i < 32 * 32; i += 512)
    ((f32x4*)wS)[i] = ((const f32x4*)(Wih + bc * 32 * 128))[i];
  __syncthreads();
  const int v = tid & 127, c0 = (tid >> 7) * 8;
  const int rot = v & 31;  // bank-derotation for embS column reads
#pragma unroll
  for (int j = 0; j < 8; ++j) {
    int c = c0 + j;
    float s = 0.f;
    for (int k = 0; k < 128; ++k) {
      int kk = (k + rot) & 127;
      s += embS[v * 128 + kk] * wS[c * 128 + kk];
    }
    int col = bc * 32 + c;
    g_emb1[v * 512 + col] = (__bf16)(s + bih[col] + bhh[col]);
  }
}

__global__ __launch_bounds__(512, 2) void lstm_ll(
    const float* __restrict__ state, const int* __restrict__ tokens,
    const float* __restrict__ W_ih, const float* __restrict__ W_hh,
    const float* __restrict__ b_ih, const float* __restrict__ b_hh,
    const float* __restrict__ W_out, const float* __restrict__ b_out,
    float* __restrict__ out) {
  // All [row][128] bf16 tiles use XOR swizzle e ^= (row&7)<<3 (bank-conflict fix).
  __shared__ __align__(16) __bf16 wih2L[512 * 128];  // 128 KB, [gatecol][k], resident
  __shared__ __align__(16) __bf16 h1L[2][32 * 128];  // 16 KB, double-buffered
  __shared__ __align__(16) __bf16 h2L[32 * 128];     // 8 KB
  __shared__ unsigned char tokL[128][32];            // 4 KB, [t][r]
  __shared__ float wsum[8][32];                      // 1 KB
  __shared__ float llL[32];

  const int tid  = threadIdx.x;
  const int w    = tid >> 6;
  const int lane = tid & 63;
  const int lr   = lane & 15;
  const int lh   = lane >> 4;
  const int b0   = blockIdx.x * 32;
  const int col  = w * 16 + lr;  // lane's column within each gate group

  // ---- one-time staging ----
  // Wih2 (layer-1 index): f32 -> bf16, swizzled, LDS-resident
  for (int i = tid; i < 512 * 16; i += 512) {
    int row = i >> 4, e = (i & 15) * 8;
    const float* p = W_ih + 512 * 128 + row * 128 + e;
    f32x4 x0 = *(const f32x4*)p, x1 = *(const f32x4*)(p + 4);
    bf16x8 v;
#pragma unroll
    for (int j = 0; j < 4; ++j) { v[j] = (__bf16)x0[j]; v[4 + j] = (__bf16)x1[j]; }
    *(bf16x8*)(wih2L + row * 128 + (e ^ ((row & 7) << 3))) = v;
  }
  for (int i = tid; i < 32 * 128; i += 512) {
    int r = i & 31, t = i >> 5;
    tokL[t][r] = (unsigned char)tokens[(b0 + r) * 128 + t];
    h2L[i] = (__bf16)0.0f;
  }
  if (tid < 32) llL[tid] = 0.0f;

  // ---- resident register weights ----
  auto ldw8 = [&](const float* p) -> bf16x8 {
    f32x4 x0 = *(const f32x4*)p, x1 = *(const f32x4*)(p + 4);
    bf16x8 v;
#pragma unroll
    for (int j = 0; j < 4; ++j) { v[j] = (__bf16)x0[j]; v[4 + j] = (__bf16)x1[j]; }
    return v;
  };
  bf16x8 whh1[4][4], whh2[4][4], woutF[4];
#pragma unroll
  for (int kc = 0; kc < 4; ++kc) {
#pragma unroll
    for (int gg = 0; gg < 4; ++gg) {
      whh1[kc][gg] = ldw8(W_hh + (gg * 128 + col) * 128 + kc * 32 + lh * 8);
      whh2[kc][gg] = ldw8(W_hh + 512 * 128 + (gg * 128 + col) * 128 + kc * 32 + lh * 8);
    }
    woutF[kc] = ldw8(W_out + col * 128 + kc * 32 + lh * 8);
  }
  float bias1v[4], bias2v[4];
#pragma unroll
  for (int gg = 0; gg < 4; ++gg) {
    bias1v[gg] = b_ih[gg * 128 + col] + b_hh[gg * 128 + col];
    bias2v[gg] = b_ih[512 + gg * 128 + col] + b_hh[512 + gg * 128 + col];
  }
  const float bo = b_out[col];
  float c1[2][4] = {}, c2[2][4] = {};
  const float z4[4] = {0.f, 0.f, 0.f, 0.f};

  f32x4 acc[2][4];
  auto zacc = [&]() {
#pragma unroll
    for (int mf = 0; mf < 2; ++mf)
#pragma unroll
      for (int gg = 0; gg < 4; ++gg) acc[mf][gg] = f32x4{0.f, 0.f, 0.f, 0.f};
  };
  auto ldsA = [&](const __bf16* buf, int row, int kc) -> bf16x8 {
    return *(const bf16x8*)(buf + row * 128 + ((kc * 32 + lh * 8) ^ ((row & 7) << 3)));
  };

  // layer-2 gates: Wih2(LDS) x h1cur + Whh2(reg) x h2L
  auto g2phase = [&](const __bf16* h1cur) {
    zacc();
#pragma unroll
    for (int kc = 0; kc < 4; ++kc) {
      bf16x8 a0 = ldsA(h1cur, lr, kc), a1 = ldsA(h1cur, 16 + lr, kc);
      bf16x8 d0 = ldsA(h2L, lr, kc), d1 = ldsA(h2L, 16 + lr, kc);
#pragma unroll
      for (int gg = 0; gg < 4; ++gg) {
        bf16x8 bi = *(const bf16x8*)(wih2L + (gg * 128 + col) * 128 +
                                     ((kc * 32 + lh * 8) ^ ((col & 7) << 3)));
        acc[0][gg] = __builtin_amdgcn_mfma_f32_16x16x32_bf16(a0, bi, acc[0][gg], 0, 0, 0);
        acc[1][gg] = __builtin_amdgcn_mfma_f32_16x16x32_bf16(a1, bi, acc[1][gg], 0, 0, 0);
        acc[0][gg] = __builtin_amdgcn_mfma_f32_16x16x32_bf16(d0, whh2[kc][gg], acc[0][gg], 0, 0, 0);
        acc[1][gg] = __builtin_amdgcn_mfma_f32_16x16x32_bf16(d1, whh2[kc][gg], acc[1][gg], 0, 0, 0);
      }
    }
  };

  // LSTM cell elementwise; C/D mapping: row = mf*16+lh*4+j, col = w*16+lr
  auto elem = [&](const float* b4, float (&c)[2][4], __bf16* hout) {
#pragma unroll
    for (int mf = 0; mf < 2; ++mf)
#pragma unroll
      for (int j = 0; j < 4; ++j) {
        float gi = acc[mf][0][j] + b4[0];
        float gf = acc[mf][1][j] + b4[1];
        float gc = acc[mf][2][j] + b4[2];
        float go = acc[mf][3][j] + b4[3];
        float cc = fsig(gf) * c[mf][j] + fsig(gi) * ftanh(gc);
        c[mf][j] = cc;
        float h = fsig(go) * ftanh(cc);
        int r = mf * 16 + lh * 4 + j;
        hout[r * 128 + (col ^ ((r & 7) << 3))] = (__bf16)h;
      }
  };

  // logits + sum-exp (no max pass: |logit| <= ~11.4, exp cannot overflow)
  auto logits = [&](int t) {
    f32x4 la[2];
    la[0] = f32x4{0.f, 0.f, 0.f, 0.f};
    la[1] = f32x4{0.f, 0.f, 0.f, 0.f};
#pragma unroll
    for (int kc = 0; kc < 4; ++kc) {
      bf16x8 a0 = ldsA(h2L, lr, kc), a1 = ldsA(h2L, 16 + lr, kc);
      la[0] = __builtin_amdgcn_mfma_f32_16x16x32_bf16(a0, woutF[kc], la[0], 0, 0, 0);
      la[1] = __builtin_amdgcn_mfma_f32_16x16x32_bf16(a1, woutF[kc], la[1], 0, 0, 0);
    }
    float lv[2][4];
#pragma unroll
    for (int mf = 0; mf < 2; ++mf)
#pragma unroll
      for (int j = 0; j < 4; ++j) {
        float v = la[mf][j] + bo;
        lv[mf][j] = v;
        float s = __expf(v);
        s += __shfl_xor(s, 1);
        s += __shfl_xor(s, 2);
        s += __shfl_xor(s, 4);
        s += __shfl_xor(s, 8);
        if (lr == 0) wsum[w][mf * 16 + lh * 4 + j] = s;
      }
    __syncthreads();  // BAR d
#pragma unroll
    for (int mf = 0; mf < 2; ++mf)
#pragma unroll
      for (int j = 0; j < 4; ++j) {
        int r = mf * 16 + lh * 4 + j;
        int tgt = (int)tokL[t + 1][r];
        if ((tgt >> 4) == w && (tgt & 15) == lr) {
          float S = 0.f;
#pragma unroll
          for (int ww = 0; ww < 8; ++ww) S += wsum[ww][r];
          llL[r] += lv[mf][j] - __logf(S);
        }
      }
  };

  __syncthreads();  // staging complete

  // ---- init step (get_init_state): x = state, h = c = 0 ----
  {
    zacc();
#pragma unroll
    for (int kc = 0; kc < 4; ++kc) {
      const float* p0 = state + (size_t)(b0 + lr) * 128 + kc * 32 + lh * 8;
      const float* p1 = state + (size_t)(b0 + 16 + lr) * 128 + kc * 32 + lh * 8;
      bf16x8 a0 = ldw8(p0), a1 = ldw8(p1);
#pragma unroll
      for (int gg = 0; gg < 4; ++gg) {
        bf16x8 bw = ldw8(W_ih + (gg * 128 + col) * 128 + kc * 32 + lh * 8);
        acc[0][gg] = __builtin_amdgcn_mfma_f32_16x16x32_bf16(a0, bw, acc[0][gg], 0, 0, 0);
        acc[1][gg] = __builtin_amdgcn_mfma_f32_16x16x32_bf16(a1, bw, acc[1][gg], 0, 0, 0);
      }
    }
    elem(bias1v, c1, h1L[0]);  // Whh1 x 0 omitted
    __syncthreads();
    g2phase(h1L[0]);           // Whh2 x 0 via zeroed h2L
    __syncthreads();
    elem(bias2v, c2, h2L);
    __syncthreads();
  }

  // ---- main loop: consume token t, predict t+1 ----
#pragma unroll 1
  for (int t = 0; t < 127; ++t) {
    const __bf16* h1p = h1L[t & 1];
    __bf16* h1c = h1L[(t & 1) ^ 1];

    // layer 1: gathers (x-part from emb1 table) + Whh1 MFMA
    __bf16 gv[2][4][4];
#pragma unroll
    for (int mf = 0; mf < 2; ++mf)
#pragma unroll
      for (int j = 0; j < 4; ++j) {
        int tk = (int)tokL[t][mf * 16 + lh * 4 + j];
#pragma unroll
        for (int gg = 0; gg < 4; ++gg) gv[mf][gg][j] = g_emb1[tk * 512 + gg * 128 + col];
      }
    zacc();
#pragma unroll
    for (int kc = 0; kc < 4; ++kc) {
      bf16x8 a0 = ldsA(h1p, lr, kc), a1 = ldsA(h1p, 16 + lr, kc);
#pragma unroll
      for (int gg = 0; gg < 4; ++gg) {
        acc[0][gg] = __builtin_amdgcn_mfma_f32_16x16x32_bf16(a0, whh1[kc][gg], acc[0][gg], 0, 0, 0);
        acc[1][gg] = __builtin_amdgcn_mfma_f32_16x16x32_bf16(a1, whh1[kc][gg], acc[1][gg], 0, 0, 0);
      }
    }
#pragma unroll
    for (int mf = 0; mf < 2; ++mf)
#pragma unroll
      for (int gg = 0; gg < 4; ++gg)
#pragma unroll
        for (int j = 0; j < 4; ++j) acc[mf][gg][j] += (float)gv[mf][gg][j];
    elem(z4, c1, h1c);
    __syncthreads();  // BAR a: h1c ready

    g2phase(h1c);
    __syncthreads();  // BAR b: all h2L reads done before overwrite
    elem(bias2v, c2, h2L);
    __syncthreads();  // BAR c: h2L ready for logits

    logits(t);        // contains BAR d
  }

  __syncthreads();
  if (tid < 32) out[b0 + tid] = llL[tid];
}

extern "C" void kernel_launch(void* const* d_in, const int* in_sizes, int n_in,
                              void* d_out, int out_size, void* d_ws, size_t ws_size,
                              hipStream_t stream) {
  const float* state  = (const float*)d_in[0];
  const int*   tokens = (const int*)d_in[1];
  const float* emb    = (const float*)d_in[2];
  const float* Wih    = (const float*)d_in[3];
  const float* Whh    = (const float*)d_in[4];
  const float* bih    = (const float*)d_in[5];
  const float* bhh    = (const float*)d_in[6];
  const float* Wout   = (const float*)d_in[7];
  const float* bout   = (const float*)d_in[8];
  float* out = (float*)d_out;

  prep_emb1<<<16, 512, 0, stream>>>(emb, Wih, bih, bhh);
  lstm_ll<<<256, 512, 0, stream>>>(state, tokens, Wih, Whh, bih, bhh, Wout, bout, out);
}

// Round 3
// 1127.536 us; speedup vs baseline: 2.2265x; 1.0859x over previous
//
#include <hip/hip_runtime.h>
#include <hip/hip_bf16.h>

// LSTM-LL v3: transposed MFMA (D = [gatecol][batch]) for packed h-writes and
// cheap softmax reduction; logits software-pipelined into the next step's
// phases (3 barriers/step); exp2-domain gates (weights pre-scaled by log2e).
// B=8192, T=128, E=128, V=128, L=2. 256 blocks x 512 thr, 32 rows/block.

typedef __bf16 bf16x8 __attribute__((ext_vector_type(8)));
typedef __bf16 bf16x4 __attribute__((ext_vector_type(4)));
typedef float  f32x4  __attribute__((ext_vector_type(4)));

#define LOG2E 1.4426950408889634f
#define LN2   0.6931471805599453f

static __device__ __bf16 g_emb1[128 * 512];  // [v][gate*128+e] = (emb[v]@Wih1^T + b1) * rowscale

__device__ __forceinline__ float frcp(float x) {
#if __has_builtin(__builtin_amdgcn_rcpf)
  return __builtin_amdgcn_rcpf(x);
#else
  return 1.0f / x;
#endif
}
__device__ __forceinline__ float fexp2(float x) {
#if __has_builtin(__builtin_amdgcn_exp2f)
  return __builtin_amdgcn_exp2f(x);
#else
  return exp2f(x);
#endif
}
__device__ __forceinline__ float flog2(float x) {
#if __has_builtin(__builtin_amdgcn_logf)
  return __builtin_amdgcn_logf(x);
#else
  return log2f(x);
#endif
}

// emb1[v][col] = (dot(emb[v,:], Wih1[col,:]) + bih1[col] + bhh1[col]) * scale(gate)
__global__ void prep_emb1(const float* __restrict__ emb, const float* __restrict__ Wih,
                          const float* __restrict__ bih, const float* __restrict__ bhh) {
  __shared__ float embS[128 * 128];
  __shared__ float wS[32 * 128];
  const int tid = threadIdx.x, bc = blockIdx.x;
  for (int i = tid; i < 128 * 32; i += 512) ((f32x4*)embS)[i] = ((const f32x4*)emb)[i];
  for (int i = tid; i < 32 * 32; i += 512)
    ((f32x4*)wS)[i] = ((const f32x4*)(Wih + bc * 32 * 128))[i];
  __syncthreads();
  const int v = tid & 127, c0 = (tid >> 7) * 8;
  const int rot = v & 31;
#pragma unroll
  for (int j = 0; j < 8; ++j) {
    int c = c0 + j;
    float s = 0.f;
    for (int k = 0; k < 128; ++k) {
      int kk = (k + rot) & 127;
      s += embS[v * 128 + kk] * wS[c * 128 + kk];
    }
    int col = bc * 32 + c;
    float sc = ((col >> 7) == 2) ? 2.0f * LOG2E : LOG2E;
    g_emb1[v * 512 + col] = (__bf16)((s + bih[col] + bhh[col]) * sc);
  }
}

__global__ __launch_bounds__(512, 2) void lstm_ll(
    const float* __restrict__ state, const int* __restrict__ tokens,
    const float* __restrict__ W_ih, const float* __restrict__ W_hh,
    const float* __restrict__ b_ih, const float* __restrict__ b_hh,
    const float* __restrict__ W_out, const float* __restrict__ b_out,
    float* __restrict__ out) {
  // [row][128] bf16 tiles: XOR swizzle e ^= (row&7)<<3 (bank-conflict fix).
  __shared__ __align__(16) __bf16 wih2L[512 * 128];  // 128 KB resident
  __shared__ __align__(16) __bf16 h1L[2][32 * 128];  // 16 KB dbuf
  __shared__ __align__(16) __bf16 h2L[32 * 128];     // 8 KB
  __shared__ unsigned char tokL[128][32];            // 4 KB [t][r]
  __shared__ float wsum[8][32];                      // 1 KB
  __shared__ float llL[32];

  const int tid  = threadIdx.x;
  const int w    = tid >> 6;
  const int lane = tid & 63;
  const int lr   = lane & 15;
  const int lh   = lane >> 4;
  const int b0   = blockIdx.x * 32;
  const int col  = w * 16 + lr;   // this lane's gate-row index (A-frag m = lr)
  const int koff = lh * 8;        // k offset within a 32-chunk
  const int e0   = w * 16 + lh * 4;  // this lane's 4 hidden units in D-frags
  const float gscA[4] = {LOG2E, LOG2E, 2.0f * LOG2E, LOG2E};
  const int sw = (lr & 7) << 3;   // swizzle for rows lr and 16+lr (same &7)

  // ---- one-time staging ----
  for (int i = tid; i < 512 * 16; i += 512) {
    int row = i >> 4, e = (i & 15) * 8;
    const float* p = W_ih + 512 * 128 + row * 128 + e;
    float sc = gscA[row >> 7];
    f32x4 x0 = *(const f32x4*)p, x1 = *(const f32x4*)(p + 4);
    bf16x8 v;
#pragma unroll
    for (int j = 0; j < 4; ++j) { v[j] = (__bf16)(x0[j] * sc); v[4 + j] = (__bf16)(x1[j] * sc); }
    *(bf16x8*)(wih2L + row * 128 + (e ^ ((row & 7) << 3))) = v;
  }
  for (int i = tid; i < 32 * 128; i += 512) {
    int r = i & 31, t = i >> 5;
    tokL[t][r] = (unsigned char)tokens[(b0 + r) * 128 + t];
  }
  if (tid < 32) llL[tid] = 0.0f;

  auto ldw8s = [&](const float* p, float sc) -> bf16x8 {
    f32x4 x0 = *(const f32x4*)p, x1 = *(const f32x4*)(p + 4);
    bf16x8 v;
#pragma unroll
    for (int j = 0; j < 4; ++j) { v[j] = (__bf16)(x0[j] * sc); v[4 + j] = (__bf16)(x1[j] * sc); }
    return v;
  };

  bf16x8 whh1[4][4], whh2[4][4], woutF[4];
#pragma unroll
  for (int kc = 0; kc < 4; ++kc) {
#pragma unroll
    for (int gg = 0; gg < 4; ++gg) {
      whh1[kc][gg] = ldw8s(W_hh + (gg * 128 + col) * 128 + kc * 32 + koff, gscA[gg]);
      whh2[kc][gg] = ldw8s(W_hh + 512 * 128 + (gg * 128 + col) * 128 + kc * 32 + koff, gscA[gg]);
    }
    woutF[kc] = ldw8s(W_out + col * 128 + kc * 32 + koff, LOG2E);
  }
  f32x4 bias2v4[4], bo4;
#pragma unroll
  for (int gg = 0; gg < 4; ++gg)
#pragma unroll
    for (int j = 0; j < 4; ++j)
      bias2v4[gg][j] = (b_ih[512 + gg * 128 + e0 + j] + b_hh[512 + gg * 128 + e0 + j]) * gscA[gg];
#pragma unroll
  for (int j = 0; j < 4; ++j) bo4[j] = b_out[e0 + j] * LOG2E;

  float c1[2][4] = {}, c2[2][4] = {};

  // B-frag (n = batch) from swizzled [32][128] LDS tile
  auto ldB = [&](const __bf16* buf, int nf, int kc) -> bf16x8 {
    return *(const bf16x8*)(buf + (nf * 16 + lr) * 128 + ((kc * 32 + koff) ^ sw));
  };

  f32x4 acc[4][2];  // [gate][batch-frag]
  auto zacc = [&]() {
#pragma unroll
    for (int gg = 0; gg < 4; ++gg)
#pragma unroll
      for (int nf = 0; nf < 2; ++nf) acc[gg][nf] = f32x4{0.f, 0.f, 0.f, 0.f};
  };

  // elem: gates (log2-domain) -> c,h ; writes 4 consecutive e per batch row (b64)
  auto elem = [&](const f32x4* b4, float (&c)[2][4], __bf16* hout) {
#pragma unroll
    for (int nf = 0; nf < 2; ++nf) {
      bf16x4 hp;
#pragma unroll
      for (int j = 0; j < 4; ++j) {
        float gi = acc[0][nf][j] + b4[0][j];
        float gf = acc[1][nf][j] + b4[1][j];
        float gc = acc[2][nf][j] + b4[2][j];
        float go = acc[3][nf][j] + b4[3][j];
        float sf = frcp(1.f + fexp2(-gf));
        float si = frcp(1.f + fexp2(-gi));
        float tg = 1.f - 2.f * frcp(fexp2(gc) + 1.f);
        float cc = sf * c[nf][j] + si * tg;
        c[nf][j] = cc;
        float so = frcp(1.f + fexp2(-go));
        float tc = 1.f - 2.f * frcp(fexp2(2.f * LOG2E * cc) + 1.f);
        hp[j] = (__bf16)(so * tc);
      }
      int b = nf * 16 + lr;
      *(bf16x4*)(hout + b * 128 + (e0 ^ ((b & 7) << 3))) = hp;
    }
  };
  const f32x4 zf4 = {0.f, 0.f, 0.f, 0.f};
  const f32x4 zb4[4] = {zf4, zf4, zf4, zf4};

  __syncthreads();  // staging complete

  // gather layer-1 per-token gate rows (packed 4-wide), for step t
  bf16x4 gv[2][4];
  auto gather = [&](int t) {
#pragma unroll
    for (int nf = 0; nf < 2; ++nf) {
      int tk = (int)tokL[t][nf * 16 + lr];
      const __bf16* pp = g_emb1 + tk * 512 + e0;
#pragma unroll
      for (int gg = 0; gg < 4; ++gg) gv[nf][gg] = *(const bf16x4*)(pp + gg * 128);
    }
  };
  gather(0);

  // ---- init step (x = state, h = c = 0) ----
  {
    zacc();
#pragma unroll
    for (int kc = 0; kc < 4; ++kc) {
      bf16x8 s0 = ldw8s(state + (size_t)(b0 + lr) * 128 + kc * 32 + koff, 1.0f);
      bf16x8 s1 = ldw8s(state + (size_t)(b0 + 16 + lr) * 128 + kc * 32 + koff, 1.0f);
#pragma unroll
      for (int gg = 0; gg < 4; ++gg) {
        bf16x8 a = ldw8s(W_ih + (gg * 128 + col) * 128 + kc * 32 + koff, gscA[gg]);
        acc[gg][0] = __builtin_amdgcn_mfma_f32_16x16x32_bf16(a, s0, acc[gg][0], 0, 0, 0);
        acc[gg][1] = __builtin_amdgcn_mfma_f32_16x16x32_bf16(a, s1, acc[gg][1], 0, 0, 0);
      }
    }
    f32x4 bias1v4[4];
#pragma unroll
    for (int gg = 0; gg < 4; ++gg)
#pragma unroll
      for (int j = 0; j < 4; ++j)
        bias1v4[gg][j] = (b_ih[gg * 128 + e0 + j] + b_hh[gg * 128 + e0 + j]) * gscA[gg];
    elem(bias1v4, c1, h1L[0]);
    __syncthreads();
    zacc();  // layer 2 init: Wih2 x h1 only (h2 = 0)
#pragma unroll
    for (int kc = 0; kc < 4; ++kc) {
      bf16x8 x0 = ldB(h1L[0], 0, kc), x1 = ldB(h1L[0], 1, kc);
#pragma unroll
      for (int gg = 0; gg < 4; ++gg) {
        bf16x8 a = *(const bf16x8*)(wih2L + (gg * 128 + col) * 128 + ((kc * 32 + koff) ^ sw));
        acc[gg][0] = __builtin_amdgcn_mfma_f32_16x16x32_bf16(a, x0, acc[gg][0], 0, 0, 0);
        acc[gg][1] = __builtin_amdgcn_mfma_f32_16x16x32_bf16(a, x1, acc[gg][1], 0, 0, 0);
      }
    }
    elem(bias2v4, c2, h2L);
    __syncthreads();
  }

  f32x4 lvA, lvB;  // pending log2-domain logits across BAR1

  // ---- pipelined main loop; iter t: act = LSTM step t, pend = logits of step t-1 ----
#pragma unroll 1
  for (int t = 0; t <= 127; ++t) {
    const bool act = (t < 127), pend = (t > 0);
    const __bf16* h1p = h1L[t & 1];
    __bf16* h1c = h1L[(t & 1) ^ 1];

    // -------- Phase A: logits-MFMA(t-1) + L1-MFMA(t) + elem1 + exp/reduce --------
    if (pend) {
      f32x4 la0 = zf4, la1 = zf4;
#pragma unroll
      for (int kc = 0; kc < 4; ++kc) {
        bf16x8 y0 = ldB(h2L, 0, kc), y1 = ldB(h2L, 1, kc);
        la0 = __builtin_amdgcn_mfma_f32_16x16x32_bf16(woutF[kc], y0, la0, 0, 0, 0);
        la1 = __builtin_amdgcn_mfma_f32_16x16x32_bf16(woutF[kc], y1, la1, 0, 0, 0);
      }
      lvA = la0 + bo4;
      lvB = la1 + bo4;
    }
    if (act) {
      zacc();
#pragma unroll
      for (int kc = 0; kc < 4; ++kc) {
        bf16x8 p0 = ldB(h1p, 0, kc), p1 = ldB(h1p, 1, kc);
#pragma unroll
        for (int gg = 0; gg < 4; ++gg) {
          acc[gg][0] = __builtin_amdgcn_mfma_f32_16x16x32_bf16(whh1[kc][gg], p0, acc[gg][0], 0, 0, 0);
          acc[gg][1] = __builtin_amdgcn_mfma_f32_16x16x32_bf16(whh1[kc][gg], p1, acc[gg][1], 0, 0, 0);
        }
      }
#pragma unroll
      for (int nf = 0; nf < 2; ++nf)
#pragma unroll
        for (int gg = 0; gg < 4; ++gg)
#pragma unroll
          for (int j = 0; j < 4; ++j) acc[gg][nf][j] += (float)gv[nf][gg][j];
    }
    if (pend) {
      float s0 = fexp2(lvA[0]) + fexp2(lvA[1]) + fexp2(lvA[2]) + fexp2(lvA[3]);
      float s1 = fexp2(lvB[0]) + fexp2(lvB[1]) + fexp2(lvB[2]) + fexp2(lvB[3]);
      s0 += __shfl_xor(s0, 16); s0 += __shfl_xor(s0, 32);
      s1 += __shfl_xor(s1, 16); s1 += __shfl_xor(s1, 32);
      if (lh == 0) { wsum[w][lr] = s0; wsum[w][16 + lr] = s1; }
    }
    if (act) elem(zb4, c1, h1c);
    __syncthreads();  // BAR1

    // -------- Phase B: g2-MFMA(t) + gather(t+1) + ll-update(t-1) --------
    if (act) {
      if (t + 1 < 127) gather(t + 1);
      zacc();
#pragma unroll
      for (int kc = 0; kc < 4; ++kc) {
        bf16x8 x0 = ldB(h1c, 0, kc), x1 = ldB(h1c, 1, kc);
        bf16x8 y0 = ldB(h2L, 0, kc), y1 = ldB(h2L, 1, kc);
#pragma unroll
        for (int gg = 0; gg < 4; ++gg) {
          bf16x8 a = *(const bf16x8*)(wih2L + (gg * 128 + col) * 128 + ((kc * 32 + koff) ^ sw));
          acc[gg][0] = __builtin_amdgcn_mfma_f32_16x16x32_bf16(a, x0, acc[gg][0], 0, 0, 0);
          acc[gg][1] = __builtin_amdgcn_mfma_f32_16x16x32_bf16(a, x1, acc[gg][1], 0, 0, 0);
          acc[gg][0] = __builtin_amdgcn_mfma_f32_16x16x32_bf16(whh2[kc][gg], y0, acc[gg][0], 0, 0, 0);
          acc[gg][1] = __builtin_amdgcn_mfma_f32_16x16x32_bf16(whh2[kc][gg], y1, acc[gg][1], 0, 0, 0);
        }
      }
    }
    if (pend) {
#pragma unroll
      for (int nf = 0; nf < 2; ++nf) {
        int r = nf * 16 + lr;
        int tgt = (int)tokL[t][r];
        if ((tgt >> 4) == w && ((tgt >> 2) & 3) == lh) {
          int j = tgt & 3;
          const f32x4& lv = nf ? lvB : lvA;
          float lvs = (j & 2) ? ((j & 1) ? lv[3] : lv[2]) : ((j & 1) ? lv[1] : lv[0]);
          float S = 0.f;
#pragma unroll
          for (int ww = 0; ww < 8; ++ww) S += wsum[ww][r];
          llL[r] += lvs - flog2(S);
        }
      }
    }
    __syncthreads();  // BAR2

    // -------- Phase C: elem2 (overwrites h2L after all readers done) --------
    if (act) elem(bias2v4, c2, h2L);
    __syncthreads();  // BAR3
  }

  if (tid < 32) out[b0 + tid] = llL[tid] * LN2;
}

extern "C" void kernel_launch(void* const* d_in, const int* in_sizes, int n_in,
                              void* d_out, int out_size, void* d_ws, size_t ws_size,
                              hipStream_t stream) {
  const float* state  = (const float*)d_in[0];
  const int*   tokens = (const int*)d_in[1];
  const float* emb    = (const float*)d_in[2];
  const float* Wih    = (const float*)d_in[3];
  const float* Whh    = (const float*)d_in[4];
  const float* bih    = (const float*)d_in[5];
  const float* bhh    = (const float*)d_in[6];
  const float* Wout   = (const float*)d_in[7];
  const float* bout   = (const float*)d_in[8];
  float* out = (float*)d_out;

  prep_emb1<<<16, 512, 0, stream>>>(emb, Wih, bih, bhh);
  lstm_ll<<<256, 512, 0, stream>>>(state, tokens, Wih, Whh, bih, bhh, Wout, bout, out);
}